// Round 9
// baseline (270.502 us; speedup 1.0000x reference)
//
#include <hip/hip_runtime.h>
#include <hip/hip_bf16.h>
#include <math.h>

typedef __bf16 bf16;
typedef __bf16 bf16x8 __attribute__((ext_vector_type(8)));
typedef __bf16 bf16x4v __attribute__((ext_vector_type(4)));
typedef short s16x4 __attribute__((ext_vector_type(4)));
typedef float f32x4 __attribute__((ext_vector_type(4)));

#define GLD16(gp, lp) __builtin_amdgcn_global_load_lds( \
    (__attribute__((address_space(1))) void*)(void*)(gp), \
    (__attribute__((address_space(3))) void*)(lp), 16, 0, 0)

#define L_SEQ 2048
#define D_MODEL 2048
#define QKV_N 3072
#define HD 128
#define QSCALE 0.1275310242959836f               // (1/sqrt(128)) * log2(e)
#define LOG2E 1.4426950408889634f

// ---------------------------------------------------------------------------
// prep: fused  (a) x f32->bf16 cast  (b) Wqkv^T cast  (c) Wo^T cast
// ---------------------------------------------------------------------------
__global__ __launch_bounds__(256) void prep(const float* __restrict__ x,
                                            const float* __restrict__ Wqkv,
                                            const float* __restrict__ Wo,
                                            bf16* __restrict__ xb,
                                            bf16* __restrict__ wqkvT,
                                            bf16* __restrict__ woT) {
    __shared__ float tile[32][33];
    int bid = blockIdx.x;
    if (bid < 4096) {                       // cast x (4M elems, 4/thread)
        int idx = (bid * 256 + threadIdx.x) * 4;
        float4 f = *(const float4*)(x + idx);
        bf16x4v o;
        o.x = (bf16)f.x; o.y = (bf16)f.y; o.z = (bf16)f.z; o.w = (bf16)f.w;
        *(bf16x4v*)(xb + idx) = o;
        return;
    }
    bid -= 4096;
    const float* src; bf16* dst; long ld_s, ld_d; int bx, by;
    if (bid < 6144) { bx = bid % 96; by = bid / 96; src = Wqkv; dst = wqkvT; ld_s = QKV_N; ld_d = D_MODEL; }
    else { bid -= 6144; bx = bid & 63; by = bid >> 6; src = Wo; dst = woT; ld_s = D_MODEL; ld_d = D_MODEL; }
    const int tx = threadIdx.x & 31, ty = threadIdx.x >> 5;
    const long c = bx * 32 + tx, r0 = by * 32;
#pragma unroll
    for (int i = 0; i < 4; ++i)
        tile[ty + i * 8][tx] = src[(r0 + ty + i * 8) * ld_s + c];
    __syncthreads();
    const long c0 = bx * 32;
#pragma unroll
    for (int i = 0; i < 4; ++i)
        dst[(c0 + ty + i * 8) * ld_d + r0 + tx] = (bf16)tile[tx][ty + i * 8];
}

// ---------------------------------------------------------------------------
// 128Mx256N GEMM body: 4 waves (2x2), wave tile 64x128 -> 32 MFMA / 12
// ds_read_b128 per wave-iter (balanced DS:MFMA).  BK=32, double-buffered
// LDS (48 KB), zero-conflict XOR swizzle (store block b at row r holds
// global block b^((r>>1)&3); read block quad^((r>>1)&3) recovers it).
// ---------------------------------------------------------------------------
#define GEMM256_BODY(KDIM)                                                       \
    __shared__ __align__(16) bf16 As[2][128 * 32];                               \
    __shared__ __align__(16) bf16 Bs[2][256 * 32];                               \
    const int tid = threadIdx.x;                                                 \
    const int wid = tid >> 6, lane = tid & 63;                                   \
    const int quad = lane >> 4, l15 = lane & 15;                                 \
    const int wm = wid & 1, wn = wid >> 1;                                       \
    const long m0 = (long)blockIdx.y * 128, n0 = (long)blockIdx.x * 256;         \
    const int srowA = wid * 32 + (lane >> 2);                                    \
    const int srowB = wid * 64 + (lane >> 2);                                    \
    const int scol = ((lane & 3) ^ ((lane >> 3) & 3)) * 8;                       \
    f32x4 acc[4][8];                                                             \
    _Pragma("unroll")                                                            \
    for (int i = 0; i < 4; ++i)                                                  \
        _Pragma("unroll")                                                        \
        for (int j = 0; j < 8; ++j) acc[i][j] = (f32x4){0.f, 0.f, 0.f, 0.f};     \
    const bf16* ApA  = A  + (m0 + srowA) * KDIM + scol;                          \
    const bf16* ApA2 = ApA + (long)16 * KDIM;                                    \
    const bf16* BpB0 = Bt + (n0 + srowB) * KDIM + scol;                          \
    const bf16* BpB1 = BpB0 + (long)16 * KDIM;                                   \
    const bf16* BpB2 = BpB0 + (long)32 * KDIM;                                   \
    const bf16* BpB3 = BpB0 + (long)48 * KDIM;                                   \
    const int rsw = ((l15 >> 1) & 3);                                            \
    auto stage = [&](int k0, int buf) {                                          \
        GLD16(ApA  + k0, &As[buf][(wid * 32) * 32]);                             \
        GLD16(ApA2 + k0, &As[buf][(wid * 32 + 16) * 32]);                        \
        GLD16(BpB0 + k0, &Bs[buf][(wid * 64) * 32]);                             \
        GLD16(BpB1 + k0, &Bs[buf][(wid * 64 + 16) * 32]);                        \
        GLD16(BpB2 + k0, &Bs[buf][(wid * 64 + 32) * 32]);                        \
        GLD16(BpB3 + k0, &Bs[buf][(wid * 64 + 48) * 32]);                        \
    };                                                                           \
    stage(0, 0);                                                                 \
    for (int k0 = 0; k0 < KDIM; k0 += 32) {                                      \
        __syncthreads();                                                         \
        if (k0 + 32 < KDIM) stage(k0 + 32, ((k0 >> 5) + 1) & 1);                 \
        const int buf = (k0 >> 5) & 1;                                           \
        bf16x8 af[4], bfr[8];                                                    \
        _Pragma("unroll")                                                        \
        for (int i = 0; i < 4; ++i)                                              \
            af[i] = *(const bf16x8*)&As[buf][(wm * 64 + i * 16 + l15) * 32 + (quad ^ rsw) * 8]; \
        _Pragma("unroll")                                                        \
        for (int j = 0; j < 8; ++j)                                              \
            bfr[j] = *(const bf16x8*)&Bs[buf][(wn * 128 + j * 16 + l15) * 32 + (quad ^ rsw) * 8]; \
        _Pragma("unroll")                                                        \
        for (int i = 0; i < 4; ++i)                                              \
            _Pragma("unroll")                                                    \
            for (int j = 0; j < 8; ++j)                                          \
                acc[i][j] = __builtin_amdgcn_mfma_f32_16x16x32_bf16(af[i], bfr[j], acc[i][j], 0, 0, 0); \
    }

// GEMM1 fused: [Q|K|V] = xb @ WqkvT, RoPE/split/V-transpose epilogue.
// head = 2*blockIdx.x + wn  (each wave's 128 cols = exactly one head).
__global__ __launch_bounds__(256, 1) void gemm_qkv(const bf16* __restrict__ A,
                                                   const bf16* __restrict__ Bt,
                                                   bf16* __restrict__ Qb,
                                                   bf16* __restrict__ Kb,
                                                   bf16* __restrict__ Vtb) {
    GEMM256_BODY(D_MODEL)

    const int head = blockIdx.x * 2 + wn;
    if (head < 20) {                                   // Q or K head: RoPE
        const float sc = head < 16 ? QSCALE : 1.0f;
        bf16* dst = head < 16 ? Qb + (long)head * L_SEQ * HD
                              : Kb + (long)(head - 16) * L_SEQ * HD;
#pragma unroll
        for (int jj = 0; jj < 2; ++jj) {               // d0 < 32: rotate
            const int d0 = jj * 16 + l15;
            const float freq = exp2f((float)d0 * (-10.0f / 31.0f));
#pragma unroll
            for (int i = 0; i < 4; ++i)
#pragma unroll
                for (int r = 0; r < 4; ++r) {
                    const long row = m0 + wm * 64 + i * 16 + quad * 4 + r;
                    float sn, cs;
                    sincosf((float)row * freq, &sn, &cs);
                    const float x1 = acc[i][jj][r], x2 = acc[i][jj + 4][r];
                    dst[row * HD + d0]      = (bf16)((x1 * cs + x2 * sn) * sc);
                    dst[row * HD + d0 + 64] = (bf16)((x2 * cs - x1 * sn) * sc);
                }
        }
#pragma unroll
        for (int jj = 2; jj < 4; ++jj) {               // 32 <= d0 < 64: identity
            const int d0 = jj * 16 + l15;
#pragma unroll
            for (int i = 0; i < 4; ++i)
#pragma unroll
                for (int r = 0; r < 4; ++r) {
                    const long row = m0 + wm * 64 + i * 16 + quad * 4 + r;
                    dst[row * HD + d0]      = (bf16)(acc[i][jj][r] * sc);
                    dst[row * HD + d0 + 64] = (bf16)(acc[i][jj + 4][r] * sc);
                }
        }
    } else {                                           // V head: write V^T[d][l]
        bf16* dst = Vtb + (long)(head - 20) * HD * L_SEQ;
#pragma unroll
        for (int i = 0; i < 4; ++i) {
            const long m = m0 + wm * 64 + i * 16 + quad * 4;
#pragma unroll
            for (int j = 0; j < 8; ++j) {
                const int d = j * 16 + l15;
                bf16x4v vv;
#pragma unroll
                for (int r = 0; r < 4; ++r) vv[r] = (bf16)acc[i][j][r];
                *(bf16x4v*)(dst + (long)d * L_SEQ + m) = vv;
            }
        }
    }
}

// GEMM2: out f32 = attnb bf16 @ woT
__global__ __launch_bounds__(256, 1) void gemm_out(const bf16* __restrict__ A,
                                                   const bf16* __restrict__ Bt,
                                                   float* __restrict__ C) {
    GEMM256_BODY(D_MODEL)
#pragma unroll
    for (int i = 0; i < 4; ++i) {
        const long m = m0 + wm * 64 + i * 16 + quad * 4;
#pragma unroll
        for (int j = 0; j < 8; ++j) {
            const long n = n0 + wn * 128 + j * 16 + l15;
#pragma unroll
            for (int r = 0; r < 4; ++r)
                C[(m + r) * (long)D_MODEL + n] = acc[i][j][r];
        }
    }
}

// ---------------------------------------------------------------------------
// GQA attention half-job kernel (unchanged from R8): each (hq, t) q-tile's
// valid k-tile list split into two alternating halves run by independent
// 256-thread blocks (grid 512 = 2 blocks/CU), heavy halves first.
// ---------------------------------------------------------------------------
__global__ __launch_bounds__(256, 2) void attn_p(const bf16* __restrict__ Qb,
                                                 const bf16* __restrict__ Kb,
                                                 const bf16* __restrict__ Vtb,
                                                 bf16* __restrict__ Opart,
                                                 float* __restrict__ lpart) {
    __shared__ __align__(1024) char smem[65536];

    const int bid = blockIdx.x;
    int t, hq, half;
    if (bid < 256) { t = bid >> 5; hq = (bid & 31) >> 1; half = bid & 1; }
    else { int b2 = bid - 256; t = 8 + (b2 >> 5); hq = (b2 & 31) >> 1; half = b2 & 1; }
    const int h = hq >> 2;
    const int q0 = t * 128;
    const int tid = threadIdx.x;
    const int w = tid >> 6;                  // wave 0..3, owns q rows w*32..+31
    const int lane = tid & 63;
    const int quad = lane >> 4, l15 = lane & 15;

    const bf16* Qg = Qb + (long)hq * L_SEQ * HD;
    const bf16* Kg = Kb + (long)h * L_SEQ * HD;
    const bf16* Vg = Vtb + (long)h * HD * L_SEQ;

    // Q as register B-frags
    bf16x8 qb[2][4];
#pragma unroll
    for (int rf = 0; rf < 2; ++rf)
#pragma unroll
        for (int kkd = 0; kkd < 4; ++kkd)
            qb[rf][kkd] = *(const bf16x8*)(Qg + (long)(q0 + w * 32 + rf * 16 + l15) * HD
                                              + kkd * 32 + quad * 8);

    f32x4 oaccT[2][8];
#pragma unroll
    for (int rf = 0; rf < 2; ++rf)
#pragma unroll
        for (int j = 0; j < 8; ++j) oaccT[rf][j] = (f32x4){0.f, 0.f, 0.f, 0.f};
    float lacc[2] = {0.f, 0.f};

    // valid 64-wide k-tiles: [0, locnt) U [2t, 32); n always even
    const int locnt = (2 * t - 14 > 0) ? (2 * t - 14) : 0;
    const int n = locnt + 32 - 2 * t;
    const int cnt = n >> 1;                  // this half-job's tile count

    auto ktile = [&](int idx) {
        const int i = 2 * idx + half;
        return (i < locnt) ? i : (2 * t + (i - locnt));
    };

    auto stage = [&](int idx, int buf) {
        const int k0 = ktile(idx) * 64;
        bf16* Ksb  = (bf16*)(smem + buf * 32768);
        bf16* Vtsb = (bf16*)(smem + buf * 32768 + 16384);
#pragma unroll
        for (int ii = 0; ii < 4; ++ii) {     // K tile: 64 keys x 128 d
            int rowb = w * 16 + ii * 4;
            int row = rowb + quad;
            GLD16(Kg + (long)(k0 + row) * HD + ((l15 ^ (row & 7)) * 8), &Ksb[rowb * 128]);
        }
#pragma unroll
        for (int ii = 0; ii < 4; ++ii) {     // V^T tile: 128 d x 64 keys
            int rowb = w * 32 + ii * 8;
            int row = rowb + (lane >> 3);
            GLD16(Vg + (long)row * L_SEQ + k0 + (((lane & 7) ^ (row & 7)) * 8), &Vtsb[rowb * 64]);
        }
    };

    stage(0, 0);

    for (int it = 0; it < cnt; ++it) {
        __syncthreads();                     // drains stage(it); prev reads done
        if (it + 1 < cnt) stage(it + 1, (it + 1) & 1);

        const int kt = ktile(it);
        const int k0 = kt * 64;
        const bf16* Ks  = (const bf16*)(smem + (it & 1) * 32768);
        const bf16* Vts = (const bf16*)(smem + (it & 1) * 32768 + 16384);

        // S^T = K Q^T : per wave 64 keys x 32 q
        f32x4 sacc[2][4];
#pragma unroll
        for (int kb = 0; kb < 4; ++kb) {
            bf16x8 ka[4];
#pragma unroll
            for (int kkd = 0; kkd < 4; ++kkd)
                ka[kkd] = *(const bf16x8*)&Ks[(kb * 16 + l15) * 128 +
                                              (((kkd * 4 + quad) ^ (l15 & 7)) * 8)];
#pragma unroll
            for (int rf = 0; rf < 2; ++rf) {
                f32x4 acc = (f32x4){0.f, 0.f, 0.f, 0.f};
#pragma unroll
                for (int kkd = 0; kkd < 4; ++kkd)
                    acc = __builtin_amdgcn_mfma_f32_16x16x32_bf16(ka[kkd], qb[rf][kkd], acc, 0, 0, 0);
                sacc[rf][kb] = acc;
            }
        }

        // mask boundary tiles + exp2 + pack P^T B-frags + l accumulate
        const bool bnd = (kt == 2 * t) || (kt == 2 * t + 1) ||
                         (kt == 2 * t - 15) || (kt == 2 * t - 16);
        s16x4 pb[2][4];
#pragma unroll
        for (int rf = 0; rf < 2; ++rf) {
            const int qq = q0 + w * 32 + rf * 16 + l15;
#pragma unroll
            for (int kb = 0; kb < 4; ++kb) {
#pragma unroll
                for (int r = 0; r < 4; ++r) {
                    float v = sacc[rf][kb][r];
                    if (bnd) {
                        const int kk = k0 + kb * 16 + quad * 4 + r;
                        if (!((kk > qq) || (kk <= qq - 1024))) v = -1e30f;
                    }
                    const float p = exp2f(v);
                    lacc[rf] += p;
                    bf16 hp = (bf16)p;
                    pb[rf][kb][r] = __builtin_bit_cast(short, hp);
                }
            }
        }

        // O^T += V^T P^T : 16x16x16 MFMA, A from LDS, B from registers
#pragma unroll
        for (int j = 0; j < 8; ++j) {
            const int drow = j * 16 + l15;
#pragma unroll
            for (int kq = 0; kq < 4; ++kq) {
                const int pc = ((kq * 2 + (quad >> 1)) ^ (l15 & 7));
                s16x4 va = *(const s16x4*)((const char*)&Vts[drow * 64] + pc * 16 + (quad & 1) * 8);
#pragma unroll
                for (int rf = 0; rf < 2; ++rf)
                    oaccT[rf][j] = __builtin_amdgcn_mfma_f32_16x16x16bf16_1k(
                        va, pb[rf][kq], oaccT[rf][j], 0, 0, 0);
            }
        }
    }

    // reduce l across quads (keys span quads)
#pragma unroll
    for (int rf = 0; rf < 2; ++rf) {
        lacc[rf] += __shfl_xor(lacc[rf], 16, 64);
        lacc[rf] += __shfl_xor(lacc[rf], 32, 64);
    }

    // write partials: Opart[bid][q 128][d 128] bf16, lpart[bid][q] f32
    bf16* Od = Opart + (long)bid * 16384;
#pragma unroll
    for (int rf = 0; rf < 2; ++rf) {
        const int ql = w * 32 + rf * 16 + l15;
#pragma unroll
        for (int j = 0; j < 8; ++j) {
            bf16x4v ov;
#pragma unroll
            for (int r = 0; r < 4; ++r) ov[r] = (bf16)oaccT[rf][j][r];
            *(bf16x4v*)(Od + ql * 128 + j * 16 + quad * 4) = ov;
        }
        if (quad == 0) lpart[bid * 128 + ql] = lacc[rf];
    }
}

// ---------------------------------------------------------------------------
// combine: attnb[q][hq*128+d] = (O0+O1) / (l0+l1+exp2(sink*log2e))
// ---------------------------------------------------------------------------
__global__ __launch_bounds__(256) void attn_combine(const bf16* __restrict__ Opart,
                                                    const float* __restrict__ lpart,
                                                    const float* __restrict__ sink,
                                                    bf16* __restrict__ attnb) {
    const int job = blockIdx.x >> 3, sub = blockIdx.x & 7;
    const int t = job >> 4, hq = job & 15;
    const int bid0 = (t < 8) ? (t * 32 + hq * 2) : (256 + (t - 8) * 32 + hq * 2);
    const int bid1 = bid0 + 1;
    const int e = sub * 2048 + threadIdx.x * 8;
    const int q = e >> 7, d0 = e & 127;
    bf16x8 o0 = *(const bf16x8*)(Opart + (long)bid0 * 16384 + q * 128 + d0);
    bf16x8 o1 = *(const bf16x8*)(Opart + (long)bid1 * 16384 + q * 128 + d0);
    const float l = lpart[bid0 * 128 + q] + lpart[bid1 * 128 + q] +
                    exp2f(sink[hq] * LOG2E);
    const float inv = 1.0f / l;
    bf16x8 ov;
#pragma unroll
    for (int r = 0; r < 8; ++r)
        ov[r] = (bf16)(((float)o0[r] + (float)o1[r]) * inv);
    *(bf16x8*)(attnb + (long)(t * 128 + q) * D_MODEL + hq * 128 + d0) = ov;
}

// ---------------------------------------------------------------------------
extern "C" void kernel_launch(void* const* d_in, const int* in_sizes, int n_in,
                              void* d_out, int out_size, void* d_ws, size_t ws_size,
                              hipStream_t stream) {
    (void)in_sizes; (void)n_in; (void)out_size; (void)ws_size;
    const float* x    = (const float*)d_in[0];
    const float* Wqkv = (const float*)d_in[1];
    const float* Wo   = (const float*)d_in[2];
    const float* s    = (const float*)d_in[3];
    float* out = (float*)d_out;

    // persistent layout (48 MB): [xb 8M][wqkvT 12.6M][Qb 8M][Kb 2M][Vtb 2M]
    //                            [woT 8M][attnb 8M]
    // Opart (16.8M bf16) + lpart (0.25M) alias [xb..wqkvT] (dead during attn).
    char* ws = (char*)d_ws;
    bf16* xb    = (bf16*)ws;
    bf16* wqkvT = (bf16*)(ws + 8388608);
    bf16* Qb    = (bf16*)(ws + 20971520);
    bf16* Kb    = (bf16*)(ws + 29360128);
    bf16* Vtb   = (bf16*)(ws + 31457280);
    bf16* woT   = (bf16*)(ws + 33554432);
    bf16* attnb = (bf16*)(ws + 41943040);
    bf16* Opart = (bf16*)ws;                  // 512 x 128 x 128 bf16
    float* lpart = (float*)(ws + 16777216);   // 512 x 128 f32

    prep<<<14336, 256, 0, stream>>>(x, Wqkv, Wo, xb, wqkvT, woT);

    gemm_qkv<<<dim3(QKV_N / 256, L_SEQ / 128), 256, 0, stream>>>(
        xb, wqkvT, Qb, Kb, Vtb);

    attn_p<<<512, 256, 0, stream>>>(Qb, Kb, Vtb, Opart, lpart);

    attn_combine<<<2048, 256, 0, stream>>>(Opart, lpart, s, attnb);

    gemm_out<<<dim3(D_MODEL / 256, L_SEQ / 128), 256, 0, stream>>>(
        attnb, woT, out);
}

// Round 10
// 230.120 us; speedup vs baseline: 1.1755x; 1.1755x over previous
//
#include <hip/hip_runtime.h>
#include <hip/hip_bf16.h>
#include <math.h>

typedef __bf16 bf16;
typedef __bf16 bf16x8 __attribute__((ext_vector_type(8)));
typedef __bf16 bf16x4v __attribute__((ext_vector_type(4)));
typedef short s16x4 __attribute__((ext_vector_type(4)));
typedef float f32x4 __attribute__((ext_vector_type(4)));

#define GLD16(gp, lp) __builtin_amdgcn_global_load_lds( \
    (__attribute__((address_space(1))) void*)(void*)(gp), \
    (__attribute__((address_space(3))) void*)(lp), 16, 0, 0)

#define L_SEQ 2048
#define D_MODEL 2048
#define QKV_N 3072
#define HD 128
#define QSCALE 0.1275310242959836f               // (1/sqrt(128)) * log2(e)
#define LOG2E 1.4426950408889634f

// ---------------------------------------------------------------------------
// prep: fused  (a) x f32->bf16 cast  (b) Wqkv^T cast  (c) Wo^T cast
// ---------------------------------------------------------------------------
__global__ __launch_bounds__(256) void prep(const float* __restrict__ x,
                                            const float* __restrict__ Wqkv,
                                            const float* __restrict__ Wo,
                                            bf16* __restrict__ xb,
                                            bf16* __restrict__ wqkvT,
                                            bf16* __restrict__ woT) {
    __shared__ float tile[32][33];
    int bid = blockIdx.x;
    if (bid < 4096) {                       // cast x (4M elems, 4/thread)
        int idx = (bid * 256 + threadIdx.x) * 4;
        float4 f = *(const float4*)(x + idx);
        bf16x4v o;
        o.x = (bf16)f.x; o.y = (bf16)f.y; o.z = (bf16)f.z; o.w = (bf16)f.w;
        *(bf16x4v*)(xb + idx) = o;
        return;
    }
    bid -= 4096;
    const float* src; bf16* dst; long ld_s, ld_d; int bx, by;
    if (bid < 6144) { bx = bid % 96; by = bid / 96; src = Wqkv; dst = wqkvT; ld_s = QKV_N; ld_d = D_MODEL; }
    else { bid -= 6144; bx = bid & 63; by = bid >> 6; src = Wo; dst = woT; ld_s = D_MODEL; ld_d = D_MODEL; }
    const int tx = threadIdx.x & 31, ty = threadIdx.x >> 5;
    const long c = bx * 32 + tx, r0 = by * 32;
#pragma unroll
    for (int i = 0; i < 4; ++i)
        tile[ty + i * 8][tx] = src[(r0 + ty + i * 8) * ld_s + c];
    __syncthreads();
    const long c0 = bx * 32;
#pragma unroll
    for (int i = 0; i < 4; ++i)
        dst[(c0 + ty + i * 8) * ld_d + r0 + tx] = (bf16)tile[tx][ty + i * 8];
}

// ---------------------------------------------------------------------------
// gemm_qkv: 128Mx128N block, 4 waves (2x2), wave tile 64x64 ->
// 8 ds_read_b128 per 16 MFMA (2:1), BK=32, double-buffered 32KB LDS,
// 1 barrier/iter.  Grid 24x16 = 384 blocks (~2/CU, 8 waves/CU).
// Block = one head (128 cols).  Wave cols interleaved: col = j*32+wn*16+l15
// so the RoPE pair (d, d+64) = (acc[i][0], acc[i][2]) sits in-lane.
// ---------------------------------------------------------------------------
__global__ __launch_bounds__(256, 2) void gemm_qkv(const bf16* __restrict__ A,
                                                   const bf16* __restrict__ Bt,
                                                   bf16* __restrict__ Qb,
                                                   bf16* __restrict__ Kb,
                                                   bf16* __restrict__ Vtb) {
    constexpr int KDIM = D_MODEL;
    __shared__ __align__(16) bf16 As[2][128 * 32];
    __shared__ __align__(16) bf16 Bs[2][128 * 32];
    const int tid = threadIdx.x;
    const int wid = tid >> 6, lane = tid & 63;
    const int quad = lane >> 4, l15 = lane & 15;
    const int wm = wid & 1, wn = wid >> 1;
    const int head = blockIdx.x;
    const long m0 = (long)blockIdx.y * 128, n0 = (long)head * 128;

    const int srow = wid * 32 + (lane >> 2);
    const int scol = ((lane & 3) ^ ((lane >> 3) & 3)) * 8;

    f32x4 acc[4][4];
#pragma unroll
    for (int i = 0; i < 4; ++i)
#pragma unroll
        for (int j = 0; j < 4; ++j) acc[i][j] = (f32x4){0.f, 0.f, 0.f, 0.f};

    const bf16* ApA  = A  + (m0 + srow) * KDIM + scol;
    const bf16* ApA2 = ApA + (long)16 * KDIM;
    const bf16* BpB  = Bt + (n0 + srow) * KDIM + scol;
    const bf16* BpB2 = BpB + (long)16 * KDIM;
    const int rsw = ((l15 >> 1) & 3);

    auto stage = [&](int k0, int buf) {
        GLD16(ApA  + k0, &As[buf][(wid * 32) * 32]);
        GLD16(ApA2 + k0, &As[buf][(wid * 32 + 16) * 32]);
        GLD16(BpB  + k0, &Bs[buf][(wid * 32) * 32]);
        GLD16(BpB2 + k0, &Bs[buf][(wid * 32 + 16) * 32]);
    };
    stage(0, 0);

    for (int k0 = 0; k0 < KDIM; k0 += 32) {
        __syncthreads();
        if (k0 + 32 < KDIM) stage(k0 + 32, ((k0 >> 5) + 1) & 1);
        const int buf = (k0 >> 5) & 1;
        bf16x8 af[4], bfr[4];
#pragma unroll
        for (int i = 0; i < 4; ++i)
            af[i] = *(const bf16x8*)&As[buf][(wm * 64 + i * 16 + l15) * 32 + (quad ^ rsw) * 8];
#pragma unroll
        for (int j = 0; j < 4; ++j)
            bfr[j] = *(const bf16x8*)&Bs[buf][(j * 32 + wn * 16 + l15) * 32 + (quad ^ rsw) * 8];
#pragma unroll
        for (int i = 0; i < 4; ++i)
#pragma unroll
            for (int j = 0; j < 4; ++j)
                acc[i][j] = __builtin_amdgcn_mfma_f32_16x16x32_bf16(af[i], bfr[j], acc[i][j], 0, 0, 0);
    }

    if (head < 20) {                                   // Q or K head: RoPE
        const float sc = head < 16 ? QSCALE : 1.0f;
        bf16* dst = head < 16 ? Qb + (long)head * L_SEQ * HD
                              : Kb + (long)(head - 16) * L_SEQ * HD;
        const int d0 = wn * 16 + l15;                  // rotate pair (j=0, j=2)
        const float freq = exp2f((float)d0 * (-10.0f / 31.0f));
        const int d1 = 32 + wn * 16 + l15;             // identity pair (j=1, j=3)
#pragma unroll
        for (int i = 0; i < 4; ++i)
#pragma unroll
            for (int r = 0; r < 4; ++r) {
                const long row = m0 + wm * 64 + i * 16 + quad * 4 + r;
                float sn, cs;
                sincosf((float)row * freq, &sn, &cs);
                const float x1 = acc[i][0][r], x2 = acc[i][2][r];
                bf16* p = dst + row * HD;
                p[d0]      = (bf16)((x1 * cs + x2 * sn) * sc);
                p[d0 + 64] = (bf16)((x2 * cs - x1 * sn) * sc);
                p[d1]      = (bf16)(acc[i][1][r] * sc);
                p[d1 + 64] = (bf16)(acc[i][3][r] * sc);
            }
    } else {                                           // V head: write V^T[d][l]
        bf16* dst = Vtb + (long)(head - 20) * HD * L_SEQ;
#pragma unroll
        for (int i = 0; i < 4; ++i) {
            const long m = m0 + wm * 64 + i * 16 + quad * 4;
#pragma unroll
            for (int j = 0; j < 4; ++j) {
                const int d = j * 32 + wn * 16 + l15;
                bf16x4v vv;
#pragma unroll
                for (int r = 0; r < 4; ++r) vv[r] = (bf16)acc[i][j][r];
                *(bf16x4v*)(dst + (long)d * L_SEQ + m) = vv;
            }
        }
    }
}

// ---------------------------------------------------------------------------
// gemm_out (R8 known-good 64Mx128N shape): grid (16,32)=512 blocks ~2/CU.
// ---------------------------------------------------------------------------
__global__ __launch_bounds__(256) void gemm_out(const bf16* __restrict__ A,
                                                const bf16* __restrict__ Bt,
                                                float* __restrict__ C) {
    constexpr int KDIM = D_MODEL;
    __shared__ __align__(16) bf16 As[64 * 32];
    __shared__ __align__(16) bf16 Bs[128 * 32];
    const int tid = threadIdx.x;
    const int wid = tid >> 6, lane = tid & 63;
    const int quad = lane >> 4, l15 = lane & 15;
    const long m0 = (long)blockIdx.y * 64, n0 = (long)blockIdx.x * 128;
    const int srowA = wid * 16 + (lane >> 2);
    const int srowB = wid * 32 + (lane >> 2);
    const int scol = ((lane & 3) ^ ((lane >> 3) & 3)) * 8;
    f32x4 acc[8];
#pragma unroll
    for (int j = 0; j < 8; ++j) acc[j] = (f32x4){0.f, 0.f, 0.f, 0.f};
    const bf16* Ap  = A  + (m0 + srowA) * KDIM + scol;
    const bf16* Bp  = Bt + (n0 + srowB) * KDIM + scol;
    const bf16* Bp2 = Bp + (long)16 * KDIM;
    bf16* lA  = &As[(wid * 16) * 32];
    bf16* lB  = &Bs[(wid * 32) * 32];
    bf16* lB2 = &Bs[(wid * 32 + 16) * 32];
    const int rsw = ((l15 >> 1) & 3);
    for (int k0 = 0; k0 < KDIM; k0 += 32) {
        GLD16(Ap + k0, lA);
        GLD16(Bp + k0, lB);
        GLD16(Bp2 + k0, lB2);
        __syncthreads();
        bf16x8 af = *(const bf16x8*)&As[(wid * 16 + l15) * 32 + (quad ^ rsw) * 8];
        bf16x8 bfr[8];
#pragma unroll
        for (int j = 0; j < 8; ++j)
            bfr[j] = *(const bf16x8*)&Bs[(j * 16 + l15) * 32 + (quad ^ rsw) * 8];
#pragma unroll
        for (int j = 0; j < 8; ++j)
            acc[j] = __builtin_amdgcn_mfma_f32_16x16x32_bf16(af, bfr[j], acc[j], 0, 0, 0);
        __syncthreads();
    }
#pragma unroll
    for (int j = 0; j < 8; ++j) {
        const long m = m0 + wid * 16 + quad * 4;
        const long n = n0 + j * 16 + l15;
#pragma unroll
        for (int r = 0; r < 4; ++r)
            C[(m + r) * (long)D_MODEL + n] = acc[j][r];
    }
}

// ---------------------------------------------------------------------------
// GQA attention half-job kernel (unchanged from R8).
// ---------------------------------------------------------------------------
__global__ __launch_bounds__(256, 2) void attn_p(const bf16* __restrict__ Qb,
                                                 const bf16* __restrict__ Kb,
                                                 const bf16* __restrict__ Vtb,
                                                 bf16* __restrict__ Opart,
                                                 float* __restrict__ lpart) {
    __shared__ __align__(1024) char smem[65536];

    const int bid = blockIdx.x;
    int t, hq, half;
    if (bid < 256) { t = bid >> 5; hq = (bid & 31) >> 1; half = bid & 1; }
    else { int b2 = bid - 256; t = 8 + (b2 >> 5); hq = (b2 & 31) >> 1; half = b2 & 1; }
    const int h = hq >> 2;
    const int q0 = t * 128;
    const int tid = threadIdx.x;
    const int w = tid >> 6;                  // wave 0..3, owns q rows w*32..+31
    const int lane = tid & 63;
    const int quad = lane >> 4, l15 = lane & 15;

    const bf16* Qg = Qb + (long)hq * L_SEQ * HD;
    const bf16* Kg = Kb + (long)h * L_SEQ * HD;
    const bf16* Vg = Vtb + (long)h * HD * L_SEQ;

    // Q as register B-frags
    bf16x8 qb[2][4];
#pragma unroll
    for (int rf = 0; rf < 2; ++rf)
#pragma unroll
        for (int kkd = 0; kkd < 4; ++kkd)
            qb[rf][kkd] = *(const bf16x8*)(Qg + (long)(q0 + w * 32 + rf * 16 + l15) * HD
                                              + kkd * 32 + quad * 8);

    f32x4 oaccT[2][8];
#pragma unroll
    for (int rf = 0; rf < 2; ++rf)
#pragma unroll
        for (int j = 0; j < 8; ++j) oaccT[rf][j] = (f32x4){0.f, 0.f, 0.f, 0.f};
    float lacc[2] = {0.f, 0.f};

    // valid 64-wide k-tiles: [0, locnt) U [2t, 32); n always even
    const int locnt = (2 * t - 14 > 0) ? (2 * t - 14) : 0;
    const int n = locnt + 32 - 2 * t;
    const int cnt = n >> 1;                  // this half-job's tile count

    auto ktile = [&](int idx) {
        const int i = 2 * idx + half;
        return (i < locnt) ? i : (2 * t + (i - locnt));
    };

    auto stage = [&](int idx, int buf) {
        const int k0 = ktile(idx) * 64;
        bf16* Ksb  = (bf16*)(smem + buf * 32768);
        bf16* Vtsb = (bf16*)(smem + buf * 32768 + 16384);
#pragma unroll
        for (int ii = 0; ii < 4; ++ii) {     // K tile: 64 keys x 128 d
            int rowb = w * 16 + ii * 4;
            int row = rowb + quad;
            GLD16(Kg + (long)(k0 + row) * HD + ((l15 ^ (row & 7)) * 8), &Ksb[rowb * 128]);
        }
#pragma unroll
        for (int ii = 0; ii < 4; ++ii) {     // V^T tile: 128 d x 64 keys
            int rowb = w * 32 + ii * 8;
            int row = rowb + (lane >> 3);
            GLD16(Vg + (long)row * L_SEQ + k0 + (((lane & 7) ^ (row & 7)) * 8), &Vtsb[rowb * 64]);
        }
    };

    stage(0, 0);

    for (int it = 0; it < cnt; ++it) {
        __syncthreads();                     // drains stage(it); prev reads done
        if (it + 1 < cnt) stage(it + 1, (it + 1) & 1);

        const int kt = ktile(it);
        const int k0 = kt * 64;
        const bf16* Ks  = (const bf16*)(smem + (it & 1) * 32768);
        const bf16* Vts = (const bf16*)(smem + (it & 1) * 32768 + 16384);

        // S^T = K Q^T : per wave 64 keys x 32 q
        f32x4 sacc[2][4];
#pragma unroll
        for (int kb = 0; kb < 4; ++kb) {
            bf16x8 ka[4];
#pragma unroll
            for (int kkd = 0; kkd < 4; ++kkd)
                ka[kkd] = *(const bf16x8*)&Ks[(kb * 16 + l15) * 128 +
                                              (((kkd * 4 + quad) ^ (l15 & 7)) * 8)];
#pragma unroll
            for (int rf = 0; rf < 2; ++rf) {
                f32x4 acc = (f32x4){0.f, 0.f, 0.f, 0.f};
#pragma unroll
                for (int kkd = 0; kkd < 4; ++kkd)
                    acc = __builtin_amdgcn_mfma_f32_16x16x32_bf16(ka[kkd], qb[rf][kkd], acc, 0, 0, 0);
                sacc[rf][kb] = acc;
            }
        }

        // mask boundary tiles + exp2 + pack P^T B-frags + l accumulate
        const bool bnd = (kt == 2 * t) || (kt == 2 * t + 1) ||
                         (kt == 2 * t - 15) || (kt == 2 * t - 16);
        s16x4 pb[2][4];
#pragma unroll
        for (int rf = 0; rf < 2; ++rf) {
            const int qq = q0 + w * 32 + rf * 16 + l15;
#pragma unroll
            for (int kb = 0; kb < 4; ++kb) {
#pragma unroll
                for (int r = 0; r < 4; ++r) {
                    float v = sacc[rf][kb][r];
                    if (bnd) {
                        const int kk = k0 + kb * 16 + quad * 4 + r;
                        if (!((kk > qq) || (kk <= qq - 1024))) v = -1e30f;
                    }
                    const float p = exp2f(v);
                    lacc[rf] += p;
                    bf16 hp = (bf16)p;
                    pb[rf][kb][r] = __builtin_bit_cast(short, hp);
                }
            }
        }

        // O^T += V^T P^T : 16x16x16 MFMA, A from LDS, B from registers
#pragma unroll
        for (int j = 0; j < 8; ++j) {
            const int drow = j * 16 + l15;
#pragma unroll
            for (int kq = 0; kq < 4; ++kq) {
                const int pc = ((kq * 2 + (quad >> 1)) ^ (l15 & 7));
                s16x4 va = *(const s16x4*)((const char*)&Vts[drow * 64] + pc * 16 + (quad & 1) * 8);
#pragma unroll
                for (int rf = 0; rf < 2; ++rf)
                    oaccT[rf][j] = __builtin_amdgcn_mfma_f32_16x16x16bf16_1k(
                        va, pb[rf][kq], oaccT[rf][j], 0, 0, 0);
            }
        }
    }

    // reduce l across quads (keys span quads)
#pragma unroll
    for (int rf = 0; rf < 2; ++rf) {
        lacc[rf] += __shfl_xor(lacc[rf], 16, 64);
        lacc[rf] += __shfl_xor(lacc[rf], 32, 64);
    }

    // write partials: Opart[bid][q 128][d 128] bf16, lpart[bid][q] f32
    bf16* Od = Opart + (long)bid * 16384;
#pragma unroll
    for (int rf = 0; rf < 2; ++rf) {
        const int ql = w * 32 + rf * 16 + l15;
#pragma unroll
        for (int j = 0; j < 8; ++j) {
            bf16x4v ov;
#pragma unroll
            for (int r = 0; r < 4; ++r) ov[r] = (bf16)oaccT[rf][j][r];
            *(bf16x4v*)(Od + ql * 128 + j * 16 + quad * 4) = ov;
        }
        if (quad == 0) lpart[bid * 128 + ql] = lacc[rf];
    }
}

// ---------------------------------------------------------------------------
// combine: attnb[q][hq*128+d] = (O0+O1) / (l0+l1+exp2(sink*log2e))
// ---------------------------------------------------------------------------
__global__ __launch_bounds__(256) void attn_combine(const bf16* __restrict__ Opart,
                                                    const float* __restrict__ lpart,
                                                    const float* __restrict__ sink,
                                                    bf16* __restrict__ attnb) {
    const int job = blockIdx.x >> 3, sub = blockIdx.x & 7;
    const int t = job >> 4, hq = job & 15;
    const int bid0 = (t < 8) ? (t * 32 + hq * 2) : (256 + (t - 8) * 32 + hq * 2);
    const int bid1 = bid0 + 1;
    const int e = sub * 2048 + threadIdx.x * 8;
    const int q = e >> 7, d0 = e & 127;
    bf16x8 o0 = *(const bf16x8*)(Opart + (long)bid0 * 16384 + q * 128 + d0);
    bf16x8 o1 = *(const bf16x8*)(Opart + (long)bid1 * 16384 + q * 128 + d0);
    const float l = lpart[bid0 * 128 + q] + lpart[bid1 * 128 + q] +
                    exp2f(sink[hq] * LOG2E);
    const float inv = 1.0f / l;
    bf16x8 ov;
#pragma unroll
    for (int r = 0; r < 8; ++r)
        ov[r] = (bf16)(((float)o0[r] + (float)o1[r]) * inv);
    *(bf16x8*)(attnb + (long)(t * 128 + q) * D_MODEL + hq * 128 + d0) = ov;
}

// ---------------------------------------------------------------------------
extern "C" void kernel_launch(void* const* d_in, const int* in_sizes, int n_in,
                              void* d_out, int out_size, void* d_ws, size_t ws_size,
                              hipStream_t stream) {
    (void)in_sizes; (void)n_in; (void)out_size; (void)ws_size;
    const float* x    = (const float*)d_in[0];
    const float* Wqkv = (const float*)d_in[1];
    const float* Wo   = (const float*)d_in[2];
    const float* s    = (const float*)d_in[3];
    float* out = (float*)d_out;

    // persistent layout (48 MB): [xb 8M][wqkvT 12.6M][Qb 8M][Kb 2M][Vtb 2M]
    //                            [woT 8M][attnb 8M]
    // Opart (16.8M bf16) + lpart (0.25M) alias [xb..wqkvT] (dead during attn).
    char* ws = (char*)d_ws;
    bf16* xb    = (bf16*)ws;
    bf16* wqkvT = (bf16*)(ws + 8388608);
    bf16* Qb    = (bf16*)(ws + 20971520);
    bf16* Kb    = (bf16*)(ws + 29360128);
    bf16* Vtb   = (bf16*)(ws + 31457280);
    bf16* woT   = (bf16*)(ws + 33554432);
    bf16* attnb = (bf16*)(ws + 41943040);
    bf16* Opart = (bf16*)ws;                  // 512 x 128 x 128 bf16
    float* lpart = (float*)(ws + 16777216);   // 512 x 128 f32

    prep<<<14336, 256, 0, stream>>>(x, Wqkv, Wo, xb, wqkvT, woT);

    gemm_qkv<<<dim3(QKV_N / 128, L_SEQ / 128), 256, 0, stream>>>(
        xb, wqkvT, Qb, Kb, Vtb);

    attn_p<<<512, 256, 0, stream>>>(Qb, Kb, Vtb, Opart, lpart);

    attn_combine<<<2048, 256, 0, stream>>>(Opart, lpart, s, attnb);

    gemm_out<<<dim3(D_MODEL / 128, L_SEQ / 64), 256, 0, stream>>>(
        attnb, woT, out);
}

// Round 11
// 218.219 us; speedup vs baseline: 1.2396x; 1.0545x over previous
//
#include <hip/hip_runtime.h>
#include <hip/hip_bf16.h>
#include <math.h>

typedef __bf16 bf16;
typedef __bf16 bf16x8 __attribute__((ext_vector_type(8)));
typedef __bf16 bf16x4v __attribute__((ext_vector_type(4)));
typedef short s16x4 __attribute__((ext_vector_type(4)));
typedef float f32x4 __attribute__((ext_vector_type(4)));

#define GLD16(gp, lp) __builtin_amdgcn_global_load_lds( \
    (__attribute__((address_space(1))) void*)(void*)(gp), \
    (__attribute__((address_space(3))) void*)(lp), 16, 0, 0)

#define L_SEQ 2048
#define D_MODEL 2048
#define QKV_N 3072
#define HD 128
#define QSCALE 0.1275310242959836f               // (1/sqrt(128)) * log2(e)
#define LOG2E 1.4426950408889634f

// ---------------------------------------------------------------------------
// prep: fused  (a) x f32->bf16 cast  (b) Wqkv^T cast  (c) Wo^T cast
// ---------------------------------------------------------------------------
__global__ __launch_bounds__(256) void prep(const float* __restrict__ x,
                                            const float* __restrict__ Wqkv,
                                            const float* __restrict__ Wo,
                                            bf16* __restrict__ xb,
                                            bf16* __restrict__ wqkvT,
                                            bf16* __restrict__ woT) {
    __shared__ float tile[32][33];
    int bid = blockIdx.x;
    if (bid < 4096) {                       // cast x (4M elems, 4/thread)
        int idx = (bid * 256 + threadIdx.x) * 4;
        float4 f = *(const float4*)(x + idx);
        bf16x4v o;
        o.x = (bf16)f.x; o.y = (bf16)f.y; o.z = (bf16)f.z; o.w = (bf16)f.w;
        *(bf16x4v*)(xb + idx) = o;
        return;
    }
    bid -= 4096;
    const float* src; bf16* dst; long ld_s, ld_d; int bx, by;
    if (bid < 6144) { bx = bid % 96; by = bid / 96; src = Wqkv; dst = wqkvT; ld_s = QKV_N; ld_d = D_MODEL; }
    else { bid -= 6144; bx = bid & 63; by = bid >> 6; src = Wo; dst = woT; ld_s = D_MODEL; ld_d = D_MODEL; }
    const int tx = threadIdx.x & 31, ty = threadIdx.x >> 5;
    const long c = bx * 32 + tx, r0 = by * 32;
#pragma unroll
    for (int i = 0; i < 4; ++i)
        tile[ty + i * 8][tx] = src[(r0 + ty + i * 8) * ld_s + c];
    __syncthreads();
    const long c0 = bx * 32;
#pragma unroll
    for (int i = 0; i < 4; ++i)
        dst[(c0 + ty + i * 8) * ld_d + r0 + tx] = (bf16)tile[tx][ty + i * 8];
}

// ---------------------------------------------------------------------------
// gemm_qkv: 128Mx128N block, 4 waves (2x2), wave tile 64x64, **BK=64**:
// 32 K-iterations (half the barrier drains of BK=32), 16 ds_read_b128 per
// 32 MFMA per wave-iter, double-buffered 64KB LDS (2 blocks/CU), 1 barrier/it.
// LDS layout: [row][64] (128B rows, bank-invariant); chunk XOR swizzle
// srcChunk=(lane&7)^(row&7) at store, position=(ks*4+quad)^(l15&7) at read ->
// 2 lanes/bank per quad-phase = conflict-free (same algebra as measured-0
// BK=32 pattern).  Block = one head; wave cols interleaved so the RoPE pair
// (d, d+64) = (acc[i][0], acc[i][2]) sits in-lane.
// ---------------------------------------------------------------------------
__global__ __launch_bounds__(256, 2) void gemm_qkv(const bf16* __restrict__ A,
                                                   const bf16* __restrict__ Bt,
                                                   bf16* __restrict__ Qb,
                                                   bf16* __restrict__ Kb,
                                                   bf16* __restrict__ Vtb) {
    constexpr int KDIM = D_MODEL;
    __shared__ __align__(16) bf16 As[2][128 * 64];
    __shared__ __align__(16) bf16 Bs[2][128 * 64];
    const int tid = threadIdx.x;
    const int wid = tid >> 6, lane = tid & 63;
    const int quad = lane >> 4, l15 = lane & 15;
    const int wm = wid & 1, wn = wid >> 1;
    const int head = blockIdx.x;
    const long m0 = (long)blockIdx.y * 128, n0 = (long)head * 128;

    f32x4 acc[4][4];
#pragma unroll
    for (int i = 0; i < 4; ++i)
#pragma unroll
        for (int j = 0; j < 4; ++j) acc[i][j] = (f32x4){0.f, 0.f, 0.f, 0.f};

    // staging: 8 GLD16/wave; each GLD16 covers 8 rows x 64 cols (1 KB)
    const int srow8 = lane >> 3;             // row within 8-row group
    const int schunk = lane & 7;             // LDS chunk position

    auto stage = [&](int k0, int buf) {
#pragma unroll
        for (int ii = 0; ii < 4; ++ii) {
            const int rowb = wid * 32 + ii * 8;
            const int row = rowb + srow8;
            const int gcol = (schunk ^ (row & 7)) * 8;
            GLD16(A  + (m0 + row) * KDIM + k0 + gcol, &As[buf][rowb * 64]);
            GLD16(Bt + (n0 + row) * KDIM + k0 + gcol, &Bs[buf][rowb * 64]);
        }
    };
    stage(0, 0);

    for (int k0 = 0; k0 < KDIM; k0 += 64) {
        __syncthreads();
        if (k0 + 64 < KDIM) stage(k0 + 64, ((k0 >> 6) + 1) & 1);
        const int buf = (k0 >> 6) & 1;
#pragma unroll
        for (int ks = 0; ks < 2; ++ks) {
            const int pos = ((ks * 4 + quad) ^ (l15 & 7)) * 8;
            bf16x8 af[4], bfr[4];
#pragma unroll
            for (int i = 0; i < 4; ++i)
                af[i] = *(const bf16x8*)&As[buf][(wm * 64 + i * 16 + l15) * 64 + pos];
#pragma unroll
            for (int j = 0; j < 4; ++j)
                bfr[j] = *(const bf16x8*)&Bs[buf][(j * 32 + wn * 16 + l15) * 64 + pos];
#pragma unroll
            for (int i = 0; i < 4; ++i)
#pragma unroll
                for (int j = 0; j < 4; ++j)
                    acc[i][j] = __builtin_amdgcn_mfma_f32_16x16x32_bf16(af[i], bfr[j], acc[i][j], 0, 0, 0);
        }
    }

    if (head < 20) {                                   // Q or K head: RoPE
        const float sc = head < 16 ? QSCALE : 1.0f;
        bf16* dst = head < 16 ? Qb + (long)head * L_SEQ * HD
                              : Kb + (long)(head - 16) * L_SEQ * HD;
        const int d0 = wn * 16 + l15;                  // rotate pair (j=0, j=2)
        const float freq = exp2f((float)d0 * (-10.0f / 31.0f));
        const int d1 = 32 + wn * 16 + l15;             // identity pair (j=1, j=3)
#pragma unroll
        for (int i = 0; i < 4; ++i)
#pragma unroll
            for (int r = 0; r < 4; ++r) {
                const long row = m0 + wm * 64 + i * 16 + quad * 4 + r;
                float sn, cs;
                sincosf((float)row * freq, &sn, &cs);
                const float x1 = acc[i][0][r], x2 = acc[i][2][r];
                bf16* p = dst + row * HD;
                p[d0]      = (bf16)((x1 * cs + x2 * sn) * sc);
                p[d0 + 64] = (bf16)((x2 * cs - x1 * sn) * sc);
                p[d1]      = (bf16)(acc[i][1][r] * sc);
                p[d1 + 64] = (bf16)(acc[i][3][r] * sc);
            }
    } else {                                           // V head: write V^T[d][l]
        bf16* dst = Vtb + (long)(head - 20) * HD * L_SEQ;
#pragma unroll
        for (int i = 0; i < 4; ++i) {
            const long m = m0 + wm * 64 + i * 16 + quad * 4;
#pragma unroll
            for (int j = 0; j < 4; ++j) {
                const int d = j * 32 + wn * 16 + l15;
                bf16x4v vv;
#pragma unroll
                for (int r = 0; r < 4; ++r) vv[r] = (bf16)acc[i][j][r];
                *(bf16x4v*)(dst + (long)d * L_SEQ + m) = vv;
            }
        }
    }
}

// ---------------------------------------------------------------------------
// gemm_out (R8 known-good 64Mx128N shape): grid (16,32)=512 blocks ~2/CU.
// ---------------------------------------------------------------------------
__global__ __launch_bounds__(256) void gemm_out(const bf16* __restrict__ A,
                                                const bf16* __restrict__ Bt,
                                                float* __restrict__ C) {
    constexpr int KDIM = D_MODEL;
    __shared__ __align__(16) bf16 As[64 * 32];
    __shared__ __align__(16) bf16 Bs[128 * 32];
    const int tid = threadIdx.x;
    const int wid = tid >> 6, lane = tid & 63;
    const int quad = lane >> 4, l15 = lane & 15;
    const long m0 = (long)blockIdx.y * 64, n0 = (long)blockIdx.x * 128;
    const int srowA = wid * 16 + (lane >> 2);
    const int srowB = wid * 32 + (lane >> 2);
    const int scol = ((lane & 3) ^ ((lane >> 3) & 3)) * 8;
    f32x4 acc[8];
#pragma unroll
    for (int j = 0; j < 8; ++j) acc[j] = (f32x4){0.f, 0.f, 0.f, 0.f};
    const bf16* Ap  = A  + (m0 + srowA) * KDIM + scol;
    const bf16* Bp  = Bt + (n0 + srowB) * KDIM + scol;
    const bf16* Bp2 = Bp + (long)16 * KDIM;
    bf16* lA  = &As[(wid * 16) * 32];
    bf16* lB  = &Bs[(wid * 32) * 32];
    bf16* lB2 = &Bs[(wid * 32 + 16) * 32];
    const int rsw = ((l15 >> 1) & 3);
    for (int k0 = 0; k0 < KDIM; k0 += 32) {
        GLD16(Ap + k0, lA);
        GLD16(Bp + k0, lB);
        GLD16(Bp2 + k0, lB2);
        __syncthreads();
        bf16x8 af = *(const bf16x8*)&As[(wid * 16 + l15) * 32 + (quad ^ rsw) * 8];
        bf16x8 bfr[8];
#pragma unroll
        for (int j = 0; j < 8; ++j)
            bfr[j] = *(const bf16x8*)&Bs[(j * 16 + l15) * 32 + (quad ^ rsw) * 8];
#pragma unroll
        for (int j = 0; j < 8; ++j)
            acc[j] = __builtin_amdgcn_mfma_f32_16x16x32_bf16(af, bfr[j], acc[j], 0, 0, 0);
        __syncthreads();
    }
#pragma unroll
    for (int j = 0; j < 8; ++j) {
        const long m = m0 + wid * 16 + quad * 4;
        const long n = n0 + j * 16 + l15;
#pragma unroll
        for (int r = 0; r < 4; ++r)
            C[(m + r) * (long)D_MODEL + n] = acc[j][r];
    }
}

// ---------------------------------------------------------------------------
// GQA attention half-job kernel (unchanged from R8).
// ---------------------------------------------------------------------------
__global__ __launch_bounds__(256, 2) void attn_p(const bf16* __restrict__ Qb,
                                                 const bf16* __restrict__ Kb,
                                                 const bf16* __restrict__ Vtb,
                                                 bf16* __restrict__ Opart,
                                                 float* __restrict__ lpart) {
    __shared__ __align__(1024) char smem[65536];

    const int bid = blockIdx.x;
    int t, hq, half;
    if (bid < 256) { t = bid >> 5; hq = (bid & 31) >> 1; half = bid & 1; }
    else { int b2 = bid - 256; t = 8 + (b2 >> 5); hq = (b2 & 31) >> 1; half = b2 & 1; }
    const int h = hq >> 2;
    const int q0 = t * 128;
    const int tid = threadIdx.x;
    const int w = tid >> 6;                  // wave 0..3, owns q rows w*32..+31
    const int lane = tid & 63;
    const int quad = lane >> 4, l15 = lane & 15;

    const bf16* Qg = Qb + (long)hq * L_SEQ * HD;
    const bf16* Kg = Kb + (long)h * L_SEQ * HD;
    const bf16* Vg = Vtb + (long)h * HD * L_SEQ;

    // Q as register B-frags
    bf16x8 qb[2][4];
#pragma unroll
    for (int rf = 0; rf < 2; ++rf)
#pragma unroll
        for (int kkd = 0; kkd < 4; ++kkd)
            qb[rf][kkd] = *(const bf16x8*)(Qg + (long)(q0 + w * 32 + rf * 16 + l15) * HD
                                              + kkd * 32 + quad * 8);

    f32x4 oaccT[2][8];
#pragma unroll
    for (int rf = 0; rf < 2; ++rf)
#pragma unroll
        for (int j = 0; j < 8; ++j) oaccT[rf][j] = (f32x4){0.f, 0.f, 0.f, 0.f};
    float lacc[2] = {0.f, 0.f};

    // valid 64-wide k-tiles: [0, locnt) U [2t, 32); n always even
    const int locnt = (2 * t - 14 > 0) ? (2 * t - 14) : 0;
    const int n = locnt + 32 - 2 * t;
    const int cnt = n >> 1;                  // this half-job's tile count

    auto ktile = [&](int idx) {
        const int i = 2 * idx + half;
        return (i < locnt) ? i : (2 * t + (i - locnt));
    };

    auto stage = [&](int idx, int buf) {
        const int k0 = ktile(idx) * 64;
        bf16* Ksb  = (bf16*)(smem + buf * 32768);
        bf16* Vtsb = (bf16*)(smem + buf * 32768 + 16384);
#pragma unroll
        for (int ii = 0; ii < 4; ++ii) {     // K tile: 64 keys x 128 d
            int rowb = w * 16 + ii * 4;
            int row = rowb + quad;
            GLD16(Kg + (long)(k0 + row) * HD + ((l15 ^ (row & 7)) * 8), &Ksb[rowb * 128]);
        }
#pragma unroll
        for (int ii = 0; ii < 4; ++ii) {     // V^T tile: 128 d x 64 keys
            int rowb = w * 32 + ii * 8;
            int row = rowb + (lane >> 3);
            GLD16(Vg + (long)row * L_SEQ + k0 + (((lane & 7) ^ (row & 7)) * 8), &Vtsb[rowb * 64]);
        }
    };

    stage(0, 0);

    for (int it = 0; it < cnt; ++it) {
        __syncthreads();                     // drains stage(it); prev reads done
        if (it + 1 < cnt) stage(it + 1, (it + 1) & 1);

        const int kt = ktile(it);
        const int k0 = kt * 64;
        const bf16* Ks  = (const bf16*)(smem + (it & 1) * 32768);
        const bf16* Vts = (const bf16*)(smem + (it & 1) * 32768 + 16384);

        // S^T = K Q^T : per wave 64 keys x 32 q
        f32x4 sacc[2][4];
#pragma unroll
        for (int kb = 0; kb < 4; ++kb) {
            bf16x8 ka[4];
#pragma unroll
            for (int kkd = 0; kkd < 4; ++kkd)
                ka[kkd] = *(const bf16x8*)&Ks[(kb * 16 + l15) * 128 +
                                              (((kkd * 4 + quad) ^ (l15 & 7)) * 8)];
#pragma unroll
            for (int rf = 0; rf < 2; ++rf) {
                f32x4 acc = (f32x4){0.f, 0.f, 0.f, 0.f};
#pragma unroll
                for (int kkd = 0; kkd < 4; ++kkd)
                    acc = __builtin_amdgcn_mfma_f32_16x16x32_bf16(ka[kkd], qb[rf][kkd], acc, 0, 0, 0);
                sacc[rf][kb] = acc;
            }
        }

        // mask boundary tiles + exp2 + pack P^T B-frags + l accumulate
        const bool bnd = (kt == 2 * t) || (kt == 2 * t + 1) ||
                         (kt == 2 * t - 15) || (kt == 2 * t - 16);
        s16x4 pb[2][4];
#pragma unroll
        for (int rf = 0; rf < 2; ++rf) {
            const int qq = q0 + w * 32 + rf * 16 + l15;
#pragma unroll
            for (int kb = 0; kb < 4; ++kb) {
#pragma unroll
                for (int r = 0; r < 4; ++r) {
                    float v = sacc[rf][kb][r];
                    if (bnd) {
                        const int kk = k0 + kb * 16 + quad * 4 + r;
                        if (!((kk > qq) || (kk <= qq - 1024))) v = -1e30f;
                    }
                    const float p = exp2f(v);
                    lacc[rf] += p;
                    bf16 hp = (bf16)p;
                    pb[rf][kb][r] = __builtin_bit_cast(short, hp);
                }
            }
        }

        // O^T += V^T P^T : 16x16x16 MFMA, A from LDS, B from registers
#pragma unroll
        for (int j = 0; j < 8; ++j) {
            const int drow = j * 16 + l15;
#pragma unroll
            for (int kq = 0; kq < 4; ++kq) {
                const int pc = ((kq * 2 + (quad >> 1)) ^ (l15 & 7));
                s16x4 va = *(const s16x4*)((const char*)&Vts[drow * 64] + pc * 16 + (quad & 1) * 8);
#pragma unroll
                for (int rf = 0; rf < 2; ++rf)
                    oaccT[rf][j] = __builtin_amdgcn_mfma_f32_16x16x16bf16_1k(
                        va, pb[rf][kq], oaccT[rf][j], 0, 0, 0);
            }
        }
    }

    // reduce l across quads (keys span quads)
#pragma unroll
    for (int rf = 0; rf < 2; ++rf) {
        lacc[rf] += __shfl_xor(lacc[rf], 16, 64);
        lacc[rf] += __shfl_xor(lacc[rf], 32, 64);
    }

    // write partials: Opart[bid][q 128][d 128] bf16, lpart[bid][q] f32
    bf16* Od = Opart + (long)bid * 16384;
#pragma unroll
    for (int rf = 0; rf < 2; ++rf) {
        const int ql = w * 32 + rf * 16 + l15;
#pragma unroll
        for (int j = 0; j < 8; ++j) {
            bf16x4v ov;
#pragma unroll
            for (int r = 0; r < 4; ++r) ov[r] = (bf16)oaccT[rf][j][r];
            *(bf16x4v*)(Od + ql * 128 + j * 16 + quad * 4) = ov;
        }
        if (quad == 0) lpart[bid * 128 + ql] = lacc[rf];
    }
}

// ---------------------------------------------------------------------------
// combine: attnb[q][hq*128+d] = (O0+O1) / (l0+l1+exp2(sink*log2e))
// ---------------------------------------------------------------------------
__global__ __launch_bounds__(256) void attn_combine(const bf16* __restrict__ Opart,
                                                    const float* __restrict__ lpart,
                                                    const float* __restrict__ sink,
                                                    bf16* __restrict__ attnb) {
    const int job = blockIdx.x >> 3, sub = blockIdx.x & 7;
    const int t = job >> 4, hq = job & 15;
    const int bid0 = (t < 8) ? (t * 32 + hq * 2) : (256 + (t - 8) * 32 + hq * 2);
    const int bid1 = bid0 + 1;
    const int e = sub * 2048 + threadIdx.x * 8;
    const int q = e >> 7, d0 = e & 127;
    bf16x8 o0 = *(const bf16x8*)(Opart + (long)bid0 * 16384 + q * 128 + d0);
    bf16x8 o1 = *(const bf16x8*)(Opart + (long)bid1 * 16384 + q * 128 + d0);
    const float l = lpart[bid0 * 128 + q] + lpart[bid1 * 128 + q] +
                    exp2f(sink[hq] * LOG2E);
    const float inv = 1.0f / l;
    bf16x8 ov;
#pragma unroll
    for (int r = 0; r < 8; ++r)
        ov[r] = (bf16)(((float)o0[r] + (float)o1[r]) * inv);
    *(bf16x8*)(attnb + (long)(t * 128 + q) * D_MODEL + hq * 128 + d0) = ov;
}

// ---------------------------------------------------------------------------
extern "C" void kernel_launch(void* const* d_in, const int* in_sizes, int n_in,
                              void* d_out, int out_size, void* d_ws, size_t ws_size,
                              hipStream_t stream) {
    (void)in_sizes; (void)n_in; (void)out_size; (void)ws_size;
    const float* x    = (const float*)d_in[0];
    const float* Wqkv = (const float*)d_in[1];
    const float* Wo   = (const float*)d_in[2];
    const float* s    = (const float*)d_in[3];
    float* out = (float*)d_out;

    // persistent layout (48 MB): [xb 8M][wqkvT 12.6M][Qb 8M][Kb 2M][Vtb 2M]
    //                            [woT 8M][attnb 8M]
    // Opart (16.8M bf16) + lpart (0.25M) alias [xb..wqkvT] (dead during attn).
    char* ws = (char*)d_ws;
    bf16* xb    = (bf16*)ws;
    bf16* wqkvT = (bf16*)(ws + 8388608);
    bf16* Qb    = (bf16*)(ws + 20971520);
    bf16* Kb    = (bf16*)(ws + 29360128);
    bf16* Vtb   = (bf16*)(ws + 31457280);
    bf16* woT   = (bf16*)(ws + 33554432);
    bf16* attnb = (bf16*)(ws + 41943040);
    bf16* Opart = (bf16*)ws;                  // 512 x 128 x 128 bf16
    float* lpart = (float*)(ws + 16777216);   // 512 x 128 f32

    prep<<<14336, 256, 0, stream>>>(x, Wqkv, Wo, xb, wqkvT, woT);

    gemm_qkv<<<dim3(QKV_N / 128, L_SEQ / 128), 256, 0, stream>>>(
        xb, wqkvT, Qb, Kb, Vtb);

    attn_p<<<512, 256, 0, stream>>>(Qb, Kb, Vtb, Opart, lpart);

    attn_combine<<<2048, 256, 0, stream>>>(Opart, lpart, s, attnb);

    gemm_out<<<dim3(D_MODEL / 128, L_SEQ / 64), 256, 0, stream>>>(
        attnb, woT, out);
}